// Round 1
// baseline (2596.039 us; speedup 1.0000x reference)
//
#include <hip/hip_runtime.h>
#include <stdint.h>

// Problem constants (fixed by the reference)
#define N_NODES 113664
#define F 128
#define E_EDGES 909312
#define T_STEPS 4
#define B_GRAPHS 1024
#define NB 111   // nodes per graph = N/B

typedef __attribute__((ext_vector_type(8))) short short8;
typedef __attribute__((ext_vector_type(4))) float f32x4;

__device__ __forceinline__ unsigned short f2bf(float f) {
    uint32_t u = __float_as_uint(f);
    u = u + 0x7fffu + ((u >> 16) & 1u);   // RNE (finite values)
    return (unsigned short)(u >> 16);
}
__device__ __forceinline__ float bf2f(unsigned short u) {
    return __uint_as_float(((uint32_t)u) << 16);
}

// Swizzled LDS addressing for bf16 tiles: row-major [rows][128] bf16 (256 B/row),
// the 16B chunk (row, k0) lives at byte row*256 + ((k0*2) ^ ((row&7)<<4)).
// Breaks the stride-256B bank conflict on fragment ds_read_b128 (guide G4 / T2).
__device__ __forceinline__ int lds_off(int row, int k0) {
    return row * 256 + ((k0 * 2) ^ ((row & 7) << 4));
}

// ---------------------------------------------------------------- init
__global__ __launch_bounds__(256) void k_init(float* deg, int* cnt, int* cur,
                                              unsigned short* h) {
    int id = blockIdx.x * 256 + threadIdx.x;          // grid covers N*128 exactly
    if (id < 4 * N_NODES) { deg[id] = 1.0f; cnt[id] = 0; cur[id] = 0; }
    int i = id >> 7, j = id & 127;
    h[id] = (i == j) ? (unsigned short)0x3F80 : (unsigned short)0;  // eye(N,F) bf16
}

// ---------------------------------------------------------------- weight prep
// Wt layout: [6][col][k] bf16, slots = [Wzi, Wri, Whi, Wzh, Wrh, Whh]
__global__ __launch_bounds__(256) void k_prepw(const float* w0, const float* w1,
                                               const float* w2, const float* w3,
                                               const float* w4, const float* w5,
                                               unsigned short* Wt) {
    int id = blockIdx.x * 256 + threadIdx.x;          // 6*16384
    int g = id >> 14, c = (id >> 7) & 127, k = id & 127;
    const float* w = g == 0 ? w0 : g == 1 ? w1 : g == 2 ? w2 : g == 3 ? w3 : g == 4 ? w4 : w5;
    Wt[id] = f2bf(w[k * F + c]);                      // transpose: Wt[g][c][k] = W[k][c]
}

// ---------------------------------------------------------------- degree + in-degree hist
__global__ __launch_bounds__(256) void k_hist(const int* eis, const float* eas,
                                              float* deg, int* cnt) {
    int t = blockIdx.y;
    int e = blockIdx.x * 256 + threadIdx.x;           // grid.x*256 == E exactly
    int dst = eis[(size_t)t * 2 * E_EDGES + E_EDGES + e];
    float w = eas[(size_t)t * E_EDGES + e];
    atomicAdd(&deg[t * N_NODES + dst], w);
    atomicAdd(&cnt[t * N_NODES + dst], 1);
}

__global__ __launch_bounds__(256) void k_dinv(const float* deg, float* dinv) {
    int id = blockIdx.x * 256 + threadIdx.x;          // 4N exactly
    dinv[id] = rsqrtf(deg[id]);
}

// ---------------------------------------------------------------- 3-phase exclusive scan of cnt
__global__ __launch_bounds__(256) void k_scanA(const int* cnt, int* part) {
    int t = blockIdx.y, b = blockIdx.x, tid = threadIdx.x;
    const int4* p = (const int4*)(cnt + (size_t)t * N_NODES + b * 1024);
    int4 v = p[tid];
    int s = v.x + v.y + v.z + v.w;
    for (int off = 32; off; off >>= 1) s += __shfl_down(s, off);
    __shared__ int wsum[4];
    if ((tid & 63) == 0) wsum[tid >> 6] = s;
    __syncthreads();
    if (tid == 0) part[t * 111 + b] = wsum[0] + wsum[1] + wsum[2] + wsum[3];
}

__global__ void k_scanB(int* part, int* rowstart) {
    int t = threadIdx.x;
    if (t < 4) {
        int off = 0;
        for (int b = 0; b < 111; b++) { int v = part[t * 111 + b]; part[t * 111 + b] = off; off += v; }
        rowstart[(size_t)t * (N_NODES + 1) + N_NODES] = off;   // == E
    }
}

__global__ __launch_bounds__(256) void k_scanC(const int* cnt, const int* part, int* rowstart) {
    int t = blockIdx.y, b = blockIdx.x, tid = threadIdx.x;
    const int4* p = (const int4*)(cnt + (size_t)t * N_NODES + b * 1024);
    int4 v = p[tid];
    int p1 = v.x, p2 = v.x + v.y, p3 = p2 + v.z, tot = p3 + v.w;
    int incl = tot;
    int lane = tid & 63;
    for (int off = 1; off < 64; off <<= 1) {
        int n = __shfl_up(incl, off);
        if (lane >= off) incl += n;
    }
    __shared__ int wtot[4];
    if (lane == 63) wtot[tid >> 6] = incl;
    __syncthreads();
    int woff = 0;
    for (int w = 0; w < (tid >> 6); w++) woff += wtot[w];
    int base = part[t * 111 + b] + woff + (incl - tot);        // exclusive prefix
    int* rs = rowstart + (size_t)t * (N_NODES + 1) + b * 1024 + tid * 4;
    rs[0] = base; rs[1] = base + p1; rs[2] = base + p2; rs[3] = base + p3;
}

__global__ __launch_bounds__(256) void k_fill(const int* eis, const float* eas,
                                              const int* rowstart, int* cur,
                                              int* csr_src, float* csr_w) {
    int t = blockIdx.y;
    int e = blockIdx.x * 256 + threadIdx.x;
    int src = eis[(size_t)t * 2 * E_EDGES + e];
    int dst = eis[(size_t)t * 2 * E_EDGES + E_EDGES + e];
    float w = eas[(size_t)t * E_EDGES + e];
    int pos = atomicAdd(&cur[t * N_NODES + dst], 1);
    int slot = rowstart[(size_t)t * (N_NODES + 1) + dst] + pos;
    csr_src[(size_t)t * E_EDGES + slot] = src;
    csr_w[(size_t)t * E_EDGES + slot] = w;
}

// ---------------------------------------------------------------- GEMM A: Y = (x @ W_gate) * dinv[row]
// grid (N/128, 3), 256 thr. gate: 0=zi, 1=ri, 2=hi. Y layout [N][384] bf16.
__global__ __launch_bounds__(256) void k_gemmA(const float* __restrict__ x,
                                               const unsigned short* __restrict__ Wt,
                                               const float* __restrict__ dinv,
                                               unsigned short* __restrict__ Y) {
    __shared__ __align__(16) char smem[65536];
    char* aT = smem;            // 128x128 bf16 swizzled
    char* bT = smem + 32768;    // 128x128 bf16 swizzled
    int gate = blockIdx.y;
    int rowbase = blockIdx.x * 128;
    int tid = threadIdx.x;

    #pragma unroll
    for (int i = 0; i < 8; i++) {
        int cid = tid + i * 256;                 // 0..2047
        int row = cid >> 4, k0 = (cid & 15) * 8;
        const float4* src = (const float4*)(x + (size_t)(rowbase + row) * F + k0);
        float4 v0 = src[0], v1 = src[1];
        short8 sv;
        sv[0] = (short)f2bf(v0.x); sv[1] = (short)f2bf(v0.y);
        sv[2] = (short)f2bf(v0.z); sv[3] = (short)f2bf(v0.w);
        sv[4] = (short)f2bf(v1.x); sv[5] = (short)f2bf(v1.y);
        sv[6] = (short)f2bf(v1.z); sv[7] = (short)f2bf(v1.w);
        *(short8*)(aT + lds_off(row, k0)) = sv;
    }
    const unsigned short* wg = Wt + gate * 16384;
    #pragma unroll
    for (int i = 0; i < 8; i++) {
        int cid = tid + i * 256;
        int col = cid >> 4, k0 = (cid & 15) * 8;
        uint4 v = *(const uint4*)(wg + col * F + k0);
        *(uint4*)(bT + lds_off(col, k0)) = v;
    }
    __syncthreads();

    int wv = tid >> 6, lane = tid & 63;
    int lrow = lane & 15, lk = (lane >> 4) * 8;
    f32x4 acc[2][8] = {};
    #pragma unroll
    for (int ks = 0; ks < 4; ks++) {
        int k0 = ks * 32 + lk;
        short8 af0 = *(short8*)(aT + lds_off(wv * 32 + lrow, k0));
        short8 af1 = *(short8*)(aT + lds_off(wv * 32 + 16 + lrow, k0));
        #pragma unroll
        for (int fc = 0; fc < 8; fc++) {
            short8 bf = *(short8*)(bT + lds_off(fc * 16 + lrow, k0));
            acc[0][fc] = __builtin_amdgcn_mfma_f32_16x16x32_bf16(af0, bf, acc[0][fc], 0, 0, 0);
            acc[1][fc] = __builtin_amdgcn_mfma_f32_16x16x32_bf16(af1, bf, acc[1][fc], 0, 0, 0);
        }
    }
    int orow = (lane >> 4) * 4;
    #pragma unroll
    for (int fr = 0; fr < 2; fr++) {
        #pragma unroll
        for (int reg = 0; reg < 4; reg++) {
            int gr = rowbase + wv * 32 + fr * 16 + orow + reg;
            float dv = dinv[gr];
            #pragma unroll
            for (int fc = 0; fc < 8; fc++) {
                int gc = gate * 128 + fc * 16 + lrow;
                Y[(size_t)gr * 384 + gc] = f2bf(acc[fr][fc][reg] * dv);
            }
        }
    }
}

// ---------------------------------------------------------------- gather: AGG = dinv_i*(Y_i + sum_e w_e*Y[src]) + b
// grid (N), 192 thr: thread c2 owns cols {2*c2, 2*c2+1} of the 384-wide row.
__global__ __launch_bounds__(192) void k_gather(const unsigned short* __restrict__ Y,
                                                const int* __restrict__ rowstart,
                                                const int* __restrict__ csr_src,
                                                const float* __restrict__ csr_w,
                                                const float* __restrict__ dinv,
                                                const float* __restrict__ bzi,
                                                const float* __restrict__ bri,
                                                const float* __restrict__ bhi,
                                                unsigned short* __restrict__ AGG) {
    int i = blockIdx.x;
    int col = threadIdx.x * 2;
    int s = rowstart[i], e = rowstart[i + 1];
    ushort2 y = *(const ushort2*)(Y + (size_t)i * 384 + col);
    float a0 = bf2f(y.x), a1 = bf2f(y.y);          // self term (Y has dinv[src] folded in)
    for (int j = s; j < e; j++) {
        int src = csr_src[j];
        float w = csr_w[j];
        ushort2 m = *(const ushort2*)(Y + (size_t)src * 384 + col);
        a0 += w * bf2f(m.x);
        a1 += w * bf2f(m.y);
    }
    float dv = dinv[i];
    const float* bp = (col < 128) ? bzi : (col < 256) ? bri : bhi;
    int bc = col & 127;
    ushort2 o;
    o.x = f2bf(dv * a0 + bp[bc]);
    o.y = f2bf(dv * a1 + bp[bc + 1]);
    *(ushort2*)(AGG + (size_t)i * 384 + col) = o;
}

// ---------------------------------------------------------------- GEMM B: h@[Wzh|Wrh] -> z, hr
// grid (N/64), 256 thr, 4 waves x 16 rows. B staged per gate (48KB LDS total).
__global__ __launch_bounds__(256) void k_gemmB(const unsigned short* __restrict__ h,
                                               const unsigned short* __restrict__ Wt,
                                               const unsigned short* __restrict__ AGG,
                                               const float* __restrict__ bzh,
                                               const float* __restrict__ brh,
                                               unsigned short* __restrict__ z,
                                               unsigned short* __restrict__ hr) {
    __shared__ __align__(16) char smem[49152];
    char* aT = smem;            // 64x128 bf16
    char* bT = smem + 16384;    // 128x128 bf16 (restaged per gate)
    int rowbase = blockIdx.x * 64;
    int tid = threadIdx.x;

    #pragma unroll
    for (int i = 0; i < 4; i++) {
        int cid = tid + i * 256;                 // 0..1023
        int row = cid >> 4, k0 = (cid & 15) * 8;
        uint4 v = *(const uint4*)(h + (size_t)(rowbase + row) * F + k0);
        *(uint4*)(aT + lds_off(row, k0)) = v;
    }

    int wv = tid >> 6, lane = tid & 63;
    int lrow = lane & 15, lk = (lane >> 4) * 8;
    f32x4 acc[2][8] = {};                        // [gate][colfrag]
    for (int g2 = 0; g2 < 2; g2++) {
        if (g2) __syncthreads();                 // protect bT restage
        const unsigned short* wg = Wt + (3 + g2) * 16384;
        #pragma unroll
        for (int i = 0; i < 8; i++) {
            int cid = tid + i * 256;
            int col = cid >> 4, k0 = (cid & 15) * 8;
            uint4 v = *(const uint4*)(wg + col * F + k0);
            *(uint4*)(bT + lds_off(col, k0)) = v;
        }
        __syncthreads();
        #pragma unroll
        for (int ks = 0; ks < 4; ks++) {
            int k0 = ks * 32 + lk;
            short8 af = *(short8*)(aT + lds_off(wv * 16 + lrow, k0));
            #pragma unroll
            for (int fc = 0; fc < 8; fc++) {
                short8 bf = *(short8*)(bT + lds_off(fc * 16 + lrow, k0));
                acc[g2][fc] = __builtin_amdgcn_mfma_f32_16x16x32_bf16(af, bf, acc[g2][fc], 0, 0, 0);
            }
        }
    }
    int orow = (lane >> 4) * 4;
    #pragma unroll
    for (int g2 = 0; g2 < 2; g2++) {
        #pragma unroll
        for (int fc = 0; fc < 8; fc++) {
            int c = fc * 16 + lrow;
            #pragma unroll
            for (int reg = 0; reg < 4; reg++) {
                int gr = rowbase + wv * 16 + orow + reg;
                float v = acc[g2][fc][reg];
                if (g2 == 0) {
                    float pre = bf2f(AGG[(size_t)gr * 384 + c]) + v + bzh[c];
                    float zz = 1.0f / (1.0f + __expf(-pre));
                    z[(size_t)gr * F + c] = f2bf(zz);
                } else {
                    float pre = bf2f(AGG[(size_t)gr * 384 + 128 + c]) + v + brh[c];
                    float rr = 1.0f / (1.0f + __expf(-pre));
                    hr[(size_t)gr * F + c] = f2bf(rr * bf2f(h[(size_t)gr * F + c]));
                }
            }
        }
    }
}

// ---------------------------------------------------------------- GEMM C: hr@Whh -> cand, h_new, out_sum
// grid (N/128), 256 thr.
__global__ __launch_bounds__(256) void k_gemmC(const unsigned short* __restrict__ hr,
                                               const unsigned short* __restrict__ Wt,
                                               const unsigned short* __restrict__ AGG,
                                               const float* __restrict__ bhh,
                                               const unsigned short* __restrict__ z,
                                               unsigned short* __restrict__ h,
                                               float* __restrict__ outsum, int t) {
    __shared__ __align__(16) char smem[65536];
    char* aT = smem;
    char* bT = smem + 32768;
    int rowbase = blockIdx.x * 128;
    int tid = threadIdx.x;

    #pragma unroll
    for (int i = 0; i < 8; i++) {
        int cid = tid + i * 256;
        int row = cid >> 4, k0 = (cid & 15) * 8;
        uint4 v = *(const uint4*)(hr + (size_t)(rowbase + row) * F + k0);
        *(uint4*)(aT + lds_off(row, k0)) = v;
    }
    const unsigned short* wg = Wt + 5 * 16384;   // Whh
    #pragma unroll
    for (int i = 0; i < 8; i++) {
        int cid = tid + i * 256;
        int col = cid >> 4, k0 = (cid & 15) * 8;
        uint4 v = *(const uint4*)(wg + col * F + k0);
        *(uint4*)(bT + lds_off(col, k0)) = v;
    }
    __syncthreads();

    int wv = tid >> 6, lane = tid & 63;
    int lrow = lane & 15, lk = (lane >> 4) * 8;
    f32x4 acc[2][8] = {};
    #pragma unroll
    for (int ks = 0; ks < 4; ks++) {
        int k0 = ks * 32 + lk;
        short8 af0 = *(short8*)(aT + lds_off(wv * 32 + lrow, k0));
        short8 af1 = *(short8*)(aT + lds_off(wv * 32 + 16 + lrow, k0));
        #pragma unroll
        for (int fc = 0; fc < 8; fc++) {
            short8 bf = *(short8*)(bT + lds_off(fc * 16 + lrow, k0));
            acc[0][fc] = __builtin_amdgcn_mfma_f32_16x16x32_bf16(af0, bf, acc[0][fc], 0, 0, 0);
            acc[1][fc] = __builtin_amdgcn_mfma_f32_16x16x32_bf16(af1, bf, acc[1][fc], 0, 0, 0);
        }
    }
    int orow = (lane >> 4) * 4;
    #pragma unroll
    for (int fr = 0; fr < 2; fr++) {
        #pragma unroll
        for (int reg = 0; reg < 4; reg++) {
            int gr = rowbase + wv * 32 + fr * 16 + orow + reg;
            #pragma unroll
            for (int fc = 0; fc < 8; fc++) {
                int gc = fc * 16 + lrow;
                float pre = bf2f(AGG[(size_t)gr * 384 + 256 + gc]) + acc[fr][fc][reg] + bhh[gc];
                float cand = tanhf(pre);
                float zz = bf2f(z[(size_t)gr * F + gc]);
                float hv = bf2f(hr[(size_t)gr * F + gc]);
                float hn = (1.0f - zz) * hv;
                float o = hn + zz * cand;
                h[(size_t)gr * F + gc] = f2bf(hn);
                size_t oi = (size_t)gr * F + gc;
                outsum[oi] = (t == 0) ? o : (outsum[oi] + o);
            }
        }
    }
}

// ---------------------------------------------------------------- pool + classifier
__global__ __launch_bounds__(128) void k_pool(const float* __restrict__ outsum,
                                              const float* __restrict__ Wlin,
                                              const float* __restrict__ blin,
                                              float* __restrict__ out) {
    int g = blockIdx.x, c = threadIdx.x;
    const float* base = outsum + (size_t)g * NB * F + c;
    float s = 0.f;
    for (int r = 0; r < NB; r++) s += base[r * F];
    float pooled = s / 111.0f;
    float p0 = pooled * Wlin[c * 2 + 0];
    float p1 = pooled * Wlin[c * 2 + 1];
    for (int off = 32; off; off >>= 1) { p0 += __shfl_down(p0, off); p1 += __shfl_down(p1, off); }
    __shared__ float red[2][2];
    if ((c & 63) == 0) { red[c >> 6][0] = p0; red[c >> 6][1] = p1; }
    __syncthreads();
    if (c == 0) {
        out[g * 2 + 0] = red[0][0] + red[1][0] + blin[0];
        out[g * 2 + 1] = red[0][1] + red[1][1] + blin[1];
    }
}

// ---------------------------------------------------------------- host
extern "C" void kernel_launch(void* const* d_in, const int* in_sizes, int n_in,
                              void* d_out, int out_size, void* d_ws, size_t ws_size,
                              hipStream_t stream) {
    const float* xs   = (const float*)d_in[0];
    const float* eas  = (const float*)d_in[1];
    const int*   eis  = (const int*)d_in[2];
    // d_in[3] = batch: known to be repeat(arange(1024), 111) — not needed.
    const float* Wzi = (const float*)d_in[4];  const float* bzi = (const float*)d_in[5];
    const float* Wzh = (const float*)d_in[6];  const float* bzh = (const float*)d_in[7];
    const float* Wri = (const float*)d_in[8];  const float* bri = (const float*)d_in[9];
    const float* Wrh = (const float*)d_in[10]; const float* brh = (const float*)d_in[11];
    const float* Whi = (const float*)d_in[12]; const float* bhi = (const float*)d_in[13];
    const float* Whh = (const float*)d_in[14]; const float* bhh = (const float*)d_in[15];
    const float* Wlin = (const float*)d_in[16]; const float* blin = (const float*)d_in[17];
    float* out = (float*)d_out;

    // Workspace carve-up (~380 MB total)
    char* p = (char*)d_ws;
    auto alloc = [&](size_t bytes) { char* r = p; p += (bytes + 255) & ~(size_t)255; return r; };
    float* deg        = (float*)alloc((size_t)4 * N_NODES * 4);
    float* dinv       = (float*)alloc((size_t)4 * N_NODES * 4);
    int*   cnt        = (int*)  alloc((size_t)4 * N_NODES * 4);
    int*   cursor     = (int*)  alloc((size_t)4 * N_NODES * 4);
    int*   rowstart   = (int*)  alloc((size_t)4 * (N_NODES + 1) * 4);
    int*   partials   = (int*)  alloc((size_t)4 * 111 * 4);
    int*   csr_src    = (int*)  alloc((size_t)4 * E_EDGES * 4);
    float* csr_w      = (float*)alloc((size_t)4 * E_EDGES * 4);
    unsigned short* Wt  = (unsigned short*)alloc((size_t)6 * 16384 * 2);
    unsigned short* Y   = (unsigned short*)alloc((size_t)N_NODES * 384 * 2);
    unsigned short* AGG = (unsigned short*)alloc((size_t)N_NODES * 384 * 2);
    unsigned short* z   = (unsigned short*)alloc((size_t)N_NODES * F * 2);
    unsigned short* hr  = (unsigned short*)alloc((size_t)N_NODES * F * 2);
    unsigned short* h   = (unsigned short*)alloc((size_t)N_NODES * F * 2);
    float* outsum       = (float*)alloc((size_t)N_NODES * F * 4);

    k_init <<<dim3((N_NODES * F) / 256), dim3(256), 0, stream>>>(deg, cnt, cursor, h);
    k_prepw<<<dim3(6 * 16384 / 256), dim3(256), 0, stream>>>(Wzi, Wri, Whi, Wzh, Wrh, Whh, Wt);
    k_hist <<<dim3(E_EDGES / 256, 4), dim3(256), 0, stream>>>(eis, eas, deg, cnt);
    k_dinv <<<dim3(4 * N_NODES / 256), dim3(256), 0, stream>>>(deg, dinv);
    k_scanA<<<dim3(111, 4), dim3(256), 0, stream>>>(cnt, partials);
    k_scanB<<<dim3(1), dim3(64), 0, stream>>>(partials, rowstart);
    k_scanC<<<dim3(111, 4), dim3(256), 0, stream>>>(cnt, partials, rowstart);
    k_fill <<<dim3(E_EDGES / 256, 4), dim3(256), 0, stream>>>(eis, eas, rowstart, cursor, csr_src, csr_w);

    for (int t = 0; t < T_STEPS; t++) {
        const float* xt = xs + (size_t)t * N_NODES * F;
        const float* dv = dinv + (size_t)t * N_NODES;
        k_gemmA <<<dim3(N_NODES / 128, 3), dim3(256), 0, stream>>>(xt, Wt, dv, Y);
        k_gather<<<dim3(N_NODES), dim3(192), 0, stream>>>(Y,
                 rowstart + (size_t)t * (N_NODES + 1),
                 csr_src + (size_t)t * E_EDGES, csr_w + (size_t)t * E_EDGES,
                 dv, bzi, bri, bhi, AGG);
        k_gemmB <<<dim3(N_NODES / 64), dim3(256), 0, stream>>>(h, Wt, AGG, bzh, brh, z, hr);
        k_gemmC <<<dim3(N_NODES / 128), dim3(256), 0, stream>>>(hr, Wt, AGG, bhh, z, h, outsum, t);
    }
    k_pool<<<dim3(B_GRAPHS), dim3(128), 0, stream>>>(outsum, Wlin, blin, out);
}

// Round 3
// 1764.554 us; speedup vs baseline: 1.4712x; 1.4712x over previous
//
#include <hip/hip_runtime.h>
#include <stdint.h>

// Problem constants (fixed by the reference)
#define N_NODES 113664
#define F 128
#define E_EDGES 909312
#define T_STEPS 4
#define B_GRAPHS 1024
#define NB 111   // nodes per graph = N/B

typedef __attribute__((ext_vector_type(8))) short short8;
typedef __attribute__((ext_vector_type(4))) float f32x4;

__device__ __forceinline__ unsigned short f2bf(float f) {
    uint32_t u = __float_as_uint(f);
    u = u + 0x7fffu + ((u >> 16) & 1u);   // RNE (finite values)
    return (unsigned short)(u >> 16);
}
__device__ __forceinline__ float bf2f(unsigned short u) {
    return __uint_as_float(((uint32_t)u) << 16);
}

// Swizzled LDS addressing for bf16 tiles: row-major [rows][128] bf16 (256 B/row),
// the 16B chunk (row, k0) lives at byte row*256 + ((k0*2) ^ ((row&7)<<4)).
__device__ __forceinline__ int lds_off(int row, int k0) {
    return row * 256 + ((k0 * 2) ^ ((row & 7) << 4));
}

// ---------------------------------------------------------------- init
__global__ __launch_bounds__(256) void k_init(unsigned long long* cnt64, int* cur,
                                              unsigned short* h) {
    int id = blockIdx.x * 256 + threadIdx.x;          // grid covers N*128 exactly
    if (id < 4 * N_NODES) { cnt64[id] = 0ull; cur[id] = 0; }
    int i = id >> 7, j = id & 127;
    h[id] = (i == j) ? (unsigned short)0x3F80 : (unsigned short)0;  // eye(N,F) bf16
}

// ---------------------------------------------------------------- weight prep
// Wt1: [2][128][256] bf16 — gate g (0=z,1=r), col, k (k<128: Wi^T, k>=128: Wh^T)
// Wt2: [128][256] bf16 — col, k (k<128: Whi^T, k>=128: Whh^T)
// bias3: [384] f32 — [bzi+bzh | bri+brh | bhi+bhh]
__global__ __launch_bounds__(256) void k_prepw(const float* Wzi, const float* Wzh,
                                               const float* Wri, const float* Wrh,
                                               const float* Whi, const float* Whh,
                                               const float* bzi, const float* bzh,
                                               const float* bri, const float* brh,
                                               const float* bhi, const float* bhh,
                                               unsigned short* Wt1, unsigned short* Wt2,
                                               float* bias3) {
    int id = blockIdx.x * 256 + threadIdx.x;
    if (id < 65536) {
        int g = id >> 15, col = (id >> 8) & 127, k = id & 255;
        const float* wi = g ? Wri : Wzi;
        const float* wh = g ? Wrh : Wzh;
        float v = (k < 128) ? wi[k * F + col] : wh[(k - 128) * F + col];
        Wt1[id] = f2bf(v);
    } else if (id < 98304) {
        int j = id - 65536;
        int col = j >> 8, k = j & 255;
        float v = (k < 128) ? Whi[k * F + col] : Whh[(k - 128) * F + col];
        Wt2[j] = f2bf(v);
    } else if (id < 98688) {
        int j = id - 98304;           // 0..383
        int c = j & 127;
        float v = (j < 128) ? bzi[c] + bzh[c] : (j < 256) ? bri[c] + brh[c]
                                                          : bhi[c] + bhh[c];
        bias3[j] = v;
    }
}

// ---------------------------------------------------------------- hist: ONE packed 64-bit atomic per edge
// hi 32 bits: in-degree count; lo 32 bits: sum of w in 2^-24 fixed point.
__global__ __launch_bounds__(256) void k_hist(const int* eis, const float* eas,
                                              unsigned long long* cnt64) {
    int t = blockIdx.y;
    int e = blockIdx.x * 256 + threadIdx.x;           // grid.x*256 == E exactly
    int dst = eis[(size_t)t * 2 * E_EDGES + E_EDGES + e];
    float w = eas[(size_t)t * E_EDGES + e];
    unsigned long long inc = (1ull << 32) | (unsigned long long)(unsigned)(w * 16777216.0f + 0.5f);
    atomicAdd(&cnt64[(size_t)t * N_NODES + dst], inc);
}

__global__ __launch_bounds__(256) void k_dinv(const unsigned long long* cnt64, float* dinv) {
    int id = blockIdx.x * 256 + threadIdx.x;          // 4N exactly
    unsigned long long v = cnt64[id];
    float deg = 1.0f + (float)(unsigned)(v & 0xffffffffu) * (1.0f / 16777216.0f);
    dinv[id] = rsqrtf(deg);
}

// ---------------------------------------------------------------- 3-phase exclusive scan of cnt (hi words)
__global__ __launch_bounds__(256) void k_scanA(const unsigned long long* cnt64, int* part) {
    int t = blockIdx.y, b = blockIdx.x, tid = threadIdx.x;
    const unsigned long long* p = cnt64 + (size_t)t * N_NODES + b * 1024 + tid * 4;
    int s = (int)(p[0] >> 32) + (int)(p[1] >> 32) + (int)(p[2] >> 32) + (int)(p[3] >> 32);
    for (int off = 32; off; off >>= 1) s += __shfl_down(s, off);
    __shared__ int wsum[4];
    if ((tid & 63) == 0) wsum[tid >> 6] = s;
    __syncthreads();
    if (tid == 0) part[t * 111 + b] = wsum[0] + wsum[1] + wsum[2] + wsum[3];
}

__global__ void k_scanB(int* part, int* rowstart) {
    int t = threadIdx.x;
    if (t < 4) {
        int off = 0;
        for (int b = 0; b < 111; b++) { int v = part[t * 111 + b]; part[t * 111 + b] = off; off += v; }
        rowstart[(size_t)t * (N_NODES + 1) + N_NODES] = off;   // == E
    }
}

__global__ __launch_bounds__(256) void k_scanC(const unsigned long long* cnt64, const int* part, int* rowstart) {
    int t = blockIdx.y, b = blockIdx.x, tid = threadIdx.x;
    const unsigned long long* p = cnt64 + (size_t)t * N_NODES + b * 1024 + tid * 4;
    int c0 = (int)(p[0] >> 32), c1 = (int)(p[1] >> 32), c2 = (int)(p[2] >> 32), c3 = (int)(p[3] >> 32);
    int p1 = c0, p2 = c0 + c1, p3 = p2 + c2, tot = p3 + c3;
    int incl = tot;
    int lane = tid & 63;
    for (int off = 1; off < 64; off <<= 1) {
        int n = __shfl_up(incl, off);
        if (lane >= off) incl += n;
    }
    __shared__ int wtot[4];
    if (lane == 63) wtot[tid >> 6] = incl;
    __syncthreads();
    int woff = 0;
    for (int w = 0; w < (tid >> 6); w++) woff += wtot[w];
    int base = part[t * 111 + b] + woff + (incl - tot);        // exclusive prefix
    int* rs = rowstart + (size_t)t * (N_NODES + 1) + b * 1024 + tid * 4;
    rs[0] = base; rs[1] = base + p1; rs[2] = base + p2; rs[3] = base + p3;
}

__global__ __launch_bounds__(256) void k_fill(const int* eis, const float* eas,
                                              const int* rowstart, int* cur,
                                              int2* csrp) {
    int t = blockIdx.y;
    int e = blockIdx.x * 256 + threadIdx.x;
    int src = eis[(size_t)t * 2 * E_EDGES + e];
    int dst = eis[(size_t)t * 2 * E_EDGES + E_EDGES + e];
    float w = eas[(size_t)t * E_EDGES + e];
    int pos = atomicAdd(&cur[t * N_NODES + dst], 1);
    int slot = rowstart[(size_t)t * (N_NODES + 1) + dst] + pos;
    int2 pk; pk.x = src; pk.y = __float_as_int(w);
    csrp[(size_t)t * E_EDGES + slot] = pk;
}

// ---------------------------------------------------------------- xpre = dinv[i] * x[i]  (bf16, N x 128)
__global__ __launch_bounds__(256) void k_xpre(const float* __restrict__ x,
                                              const float* __restrict__ dinv,
                                              unsigned short* __restrict__ xpre) {
    int id = blockIdx.x * 256 + threadIdx.x;          // N/16 blocks: 8 elems/thread
    int row = id >> 4, k0 = (id & 15) * 8;
    float dv = dinv[row];
    const float4* src = (const float4*)(x + (size_t)row * F + k0);
    float4 v0 = src[0], v1 = src[1];
    short8 sv;
    sv[0] = (short)f2bf(dv * v0.x); sv[1] = (short)f2bf(dv * v0.y);
    sv[2] = (short)f2bf(dv * v0.z); sv[3] = (short)f2bf(dv * v0.w);
    sv[4] = (short)f2bf(dv * v1.x); sv[5] = (short)f2bf(dv * v1.y);
    sv[6] = (short)f2bf(dv * v1.z); sv[7] = (short)f2bf(dv * v1.w);
    *(short8*)(xpre + (size_t)row * F + k0) = sv;
}

// ---------------------------------------------------------------- prop: xagg_i = dinv_i*(xpre_i + sum_e w_e*xpre[src])
// one wave per node; lane handles 2 cols (256B/row coalesced reads)
__global__ __launch_bounds__(256) void k_prop(const unsigned short* __restrict__ xpre,
                                              const int* __restrict__ rowstart,
                                              const int2* __restrict__ csrp,
                                              const float* __restrict__ dinv,
                                              unsigned short* __restrict__ xagg) {
    int node = blockIdx.x * 4 + (threadIdx.x >> 6);
    int lane = threadIdx.x & 63;
    int s = rowstart[node], e = rowstart[node + 1];
    ushort2 sv = *(const ushort2*)(xpre + (size_t)node * F + lane * 2);
    float a0 = bf2f(sv.x), a1 = bf2f(sv.y);
    for (int j = s; j < e; j++) {
        int2 c = csrp[j];
        float w = __int_as_float(c.y);
        ushort2 m = *(const ushort2*)(xpre + (size_t)c.x * F + lane * 2);
        a0 += w * bf2f(m.x);
        a1 += w * bf2f(m.y);
    }
    float dv = dinv[node];
    ushort2 o; o.x = f2bf(dv * a0); o.y = f2bf(dv * a1);
    *(ushort2*)(xagg + (size_t)node * F + lane * 2) = o;
}

// ---------------------------------------------------------------- GEMM1: [xagg|h] @ Wt1[gate] (K=256)
// grid (N/128, 2). gate 0 -> z = sigmoid(.), gate 1 -> r = sigmoid(.), hr = r*h (h from LDS)
__global__ __launch_bounds__(256) void k_gemm1(const unsigned short* __restrict__ xagg,
                                               const unsigned short* __restrict__ h,
                                               const unsigned short* __restrict__ Wt1,
                                               const float* __restrict__ bias3,
                                               unsigned short* __restrict__ z,
                                               unsigned short* __restrict__ hr) {
    __shared__ __align__(16) char aT[32768];
    __shared__ __align__(16) char bT[32768];
    int gate = blockIdx.y;
    int rowbase = blockIdx.x * 128;
    int tid = threadIdx.x;
    int wv = tid >> 6, lane = tid & 63;
    int lrow = lane & 15, lk = (lane >> 4) * 8;
    const float* bias = bias3 + gate * 128;
    f32x4 acc[2][8] = {};
    for (int kh = 0; kh < 2; kh++) {
        if (kh) __syncthreads();
        const unsigned short* asrc = kh ? h : xagg;
        #pragma unroll
        for (int i = 0; i < 8; i++) {
            int cid = tid + i * 256;
            int row = cid >> 4, k0 = (cid & 15) * 8;
            uint4 v = *(const uint4*)(asrc + (size_t)(rowbase + row) * F + k0);
            *(uint4*)(aT + lds_off(row, k0)) = v;
        }
        #pragma unroll
        for (int i = 0; i < 8; i++) {
            int cid = tid + i * 256;
            int col = cid >> 4, k0 = (cid & 15) * 8;
            uint4 v = *(const uint4*)(Wt1 + (size_t)(gate * 128 + col) * 256 + kh * 128 + k0);
            *(uint4*)(bT + lds_off(col, k0)) = v;
        }
        __syncthreads();
        #pragma unroll
        for (int ks = 0; ks < 4; ks++) {
            int k0 = ks * 32 + lk;
            short8 af0 = *(short8*)(aT + lds_off(wv * 32 + lrow, k0));
            short8 af1 = *(short8*)(aT + lds_off(wv * 32 + 16 + lrow, k0));
            #pragma unroll
            for (int fc = 0; fc < 8; fc++) {
                short8 bf = *(short8*)(bT + lds_off(fc * 16 + lrow, k0));
                acc[0][fc] = __builtin_amdgcn_mfma_f32_16x16x32_bf16(af0, bf, acc[0][fc], 0, 0, 0);
                acc[1][fc] = __builtin_amdgcn_mfma_f32_16x16x32_bf16(af1, bf, acc[1][fc], 0, 0, 0);
            }
        }
    }
    int orow = (lane >> 4) * 4;
    #pragma unroll
    for (int fr = 0; fr < 2; fr++) {
        #pragma unroll
        for (int reg = 0; reg < 4; reg++) {
            int lr = wv * 32 + fr * 16 + orow + reg;
            int gr = rowbase + lr;
            #pragma unroll
            for (int fc = 0; fc < 8; fc++) {
                int c = fc * 16 + lrow;
                float pre = acc[fr][fc][reg] + bias[c];
                float sg = 1.0f / (1.0f + __expf(-pre));
                if (gate == 0) {
                    z[(size_t)gr * F + c] = f2bf(sg);
                } else {
                    // h[lr][c] from the staged kh=1 A tile (still valid, read-only)
                    int byte = lr * 256 + (((c >> 3) << 4) ^ ((lr & 7) << 4)) + (c & 7) * 2;
                    float hv = bf2f(*(const unsigned short*)(aT + byte));
                    hr[(size_t)gr * F + c] = f2bf(sg * hv);
                }
            }
        }
    }
}

// ---------------------------------------------------------------- GEMM2: [xagg|hr] @ Wt2 (K=256)
// cand = tanh(.); h_new = (1-z)*hr; out = h_new + z*cand; accumulate outsum
__global__ __launch_bounds__(256) void k_gemm2(const unsigned short* __restrict__ xagg,
                                               const unsigned short* __restrict__ hr_,
                                               const unsigned short* __restrict__ Wt2,
                                               const float* __restrict__ bias3,
                                               const unsigned short* __restrict__ z_,
                                               unsigned short* __restrict__ h,
                                               float* __restrict__ outsum, int t) {
    __shared__ __align__(16) char aT[32768];
    __shared__ __align__(16) char bT[32768];
    int rowbase = blockIdx.x * 128;
    int tid = threadIdx.x;
    int wv = tid >> 6, lane = tid & 63;
    int lrow = lane & 15, lk = (lane >> 4) * 8;
    const float* bias = bias3 + 256;
    f32x4 acc[2][8] = {};
    for (int kh = 0; kh < 2; kh++) {
        if (kh) __syncthreads();
        const unsigned short* asrc = kh ? hr_ : xagg;
        #pragma unroll
        for (int i = 0; i < 8; i++) {
            int cid = tid + i * 256;
            int row = cid >> 4, k0 = (cid & 15) * 8;
            uint4 v = *(const uint4*)(asrc + (size_t)(rowbase + row) * F + k0);
            *(uint4*)(aT + lds_off(row, k0)) = v;
        }
        #pragma unroll
        for (int i = 0; i < 8; i++) {
            int cid = tid + i * 256;
            int col = cid >> 4, k0 = (cid & 15) * 8;
            uint4 v = *(const uint4*)(Wt2 + (size_t)col * 256 + kh * 128 + k0);
            *(uint4*)(bT + lds_off(col, k0)) = v;
        }
        __syncthreads();
        #pragma unroll
        for (int ks = 0; ks < 4; ks++) {
            int k0 = ks * 32 + lk;
            short8 af0 = *(short8*)(aT + lds_off(wv * 32 + lrow, k0));
            short8 af1 = *(short8*)(aT + lds_off(wv * 32 + 16 + lrow, k0));
            #pragma unroll
            for (int fc = 0; fc < 8; fc++) {
                short8 bf = *(short8*)(bT + lds_off(fc * 16 + lrow, k0));
                acc[0][fc] = __builtin_amdgcn_mfma_f32_16x16x32_bf16(af0, bf, acc[0][fc], 0, 0, 0);
                acc[1][fc] = __builtin_amdgcn_mfma_f32_16x16x32_bf16(af1, bf, acc[1][fc], 0, 0, 0);
            }
        }
    }
    int orow = (lane >> 4) * 4;
    #pragma unroll
    for (int fr = 0; fr < 2; fr++) {
        #pragma unroll
        for (int reg = 0; reg < 4; reg++) {
            int lr = wv * 32 + fr * 16 + orow + reg;
            int gr = rowbase + lr;
            #pragma unroll
            for (int fc = 0; fc < 8; fc++) {
                int c = fc * 16 + lrow;
                float pre = acc[fr][fc][reg] + bias[c];
                float cand = tanhf(pre);
                float zz = bf2f(z_[(size_t)gr * F + c]);
                int byte = lr * 256 + (((c >> 3) << 4) ^ ((lr & 7) << 4)) + (c & 7) * 2;
                float hv = bf2f(*(const unsigned short*)(aT + byte));   // hr from LDS
                float hn = (1.0f - zz) * hv;
                float o = hn + zz * cand;
                h[(size_t)gr * F + c] = f2bf(hn);
                size_t oi = (size_t)gr * F + c;
                outsum[oi] = (t == 0) ? o : (outsum[oi] + o);
            }
        }
    }
}

// ---------------------------------------------------------------- pool + classifier
__global__ __launch_bounds__(128) void k_pool(const float* __restrict__ outsum,
                                              const float* __restrict__ Wlin,
                                              const float* __restrict__ blin,
                                              float* __restrict__ out) {
    int g = blockIdx.x, c = threadIdx.x;
    const float* base = outsum + (size_t)g * NB * F + c;
    float s = 0.f;
    for (int r = 0; r < NB; r++) s += base[r * F];
    float pooled = s / 111.0f;
    float p0 = pooled * Wlin[c * 2 + 0];
    float p1 = pooled * Wlin[c * 2 + 1];
    for (int off = 32; off; off >>= 1) { p0 += __shfl_down(p0, off); p1 += __shfl_down(p1, off); }
    __shared__ float red[2][2];
    if ((c & 63) == 0) { red[c >> 6][0] = p0; red[c >> 6][1] = p1; }
    __syncthreads();
    if (c == 0) {
        out[g * 2 + 0] = red[0][0] + red[1][0] + blin[0];
        out[g * 2 + 1] = red[0][1] + red[1][1] + blin[1];
    }
}

// ---------------------------------------------------------------- host
extern "C" void kernel_launch(void* const* d_in, const int* in_sizes, int n_in,
                              void* d_out, int out_size, void* d_ws, size_t ws_size,
                              hipStream_t stream) {
    const float* xs   = (const float*)d_in[0];
    const float* eas  = (const float*)d_in[1];
    const int*   eis  = (const int*)d_in[2];
    // d_in[3] = batch: repeat(arange(1024), 111) — implicit.
    const float* Wzi = (const float*)d_in[4];  const float* bzi = (const float*)d_in[5];
    const float* Wzh = (const float*)d_in[6];  const float* bzh = (const float*)d_in[7];
    const float* Wri = (const float*)d_in[8];  const float* bri = (const float*)d_in[9];
    const float* Wrh = (const float*)d_in[10]; const float* brh = (const float*)d_in[11];
    const float* Whi = (const float*)d_in[12]; const float* bhi = (const float*)d_in[13];
    const float* Whh = (const float*)d_in[14]; const float* bhh = (const float*)d_in[15];
    const float* Wlin = (const float*)d_in[16]; const float* blin = (const float*)d_in[17];
    float* out = (float*)d_out;

    char* p = (char*)d_ws;
    auto alloc = [&](size_t bytes) { char* r = p; p += (bytes + 255) & ~(size_t)255; return r; };
    unsigned long long* cnt64 = (unsigned long long*)alloc((size_t)4 * N_NODES * 8);
    int*   cursor   = (int*)  alloc((size_t)4 * N_NODES * 4);
    int*   rowstart = (int*)  alloc((size_t)4 * (N_NODES + 1) * 4);
    int*   partials = (int*)  alloc((size_t)4 * 111 * 4);
    float* dinv     = (float*)alloc((size_t)4 * N_NODES * 4);
    int2*  csrp     = (int2*) alloc((size_t)4 * E_EDGES * 8);
    unsigned short* Wt1 = (unsigned short*)alloc((size_t)65536 * 2);
    unsigned short* Wt2 = (unsigned short*)alloc((size_t)32768 * 2);
    float* bias3        = (float*)alloc((size_t)384 * 4);
    unsigned short* xpre = (unsigned short*)alloc((size_t)N_NODES * F * 2);
    unsigned short* xagg = (unsigned short*)alloc((size_t)N_NODES * F * 2);
    unsigned short* z    = (unsigned short*)alloc((size_t)N_NODES * F * 2);
    unsigned short* hr   = (unsigned short*)alloc((size_t)N_NODES * F * 2);
    unsigned short* h    = (unsigned short*)alloc((size_t)N_NODES * F * 2);
    float* outsum        = (float*)alloc((size_t)N_NODES * F * 4);

    k_init <<<dim3((N_NODES * F) / 256), dim3(256), 0, stream>>>(cnt64, cursor, h);
    k_prepw<<<dim3(386), dim3(256), 0, stream>>>(Wzi, Wzh, Wri, Wrh, Whi, Whh,
                                                 bzi, bzh, bri, brh, bhi, bhh,
                                                 Wt1, Wt2, bias3);
    k_hist <<<dim3(E_EDGES / 256, 4), dim3(256), 0, stream>>>(eis, eas, cnt64);
    k_dinv <<<dim3(4 * N_NODES / 256), dim3(256), 0, stream>>>(cnt64, dinv);
    k_scanA<<<dim3(111, 4), dim3(256), 0, stream>>>(cnt64, partials);
    k_scanB<<<dim3(1), dim3(64), 0, stream>>>(partials, rowstart);
    k_scanC<<<dim3(111, 4), dim3(256), 0, stream>>>(cnt64, partials, rowstart);
    k_fill <<<dim3(E_EDGES / 256, 4), dim3(256), 0, stream>>>(eis, eas, rowstart, cursor, csrp);

    for (int t = 0; t < T_STEPS; t++) {
        const float* xt = xs + (size_t)t * N_NODES * F;
        const float* dv = dinv + (size_t)t * N_NODES;
        k_xpre <<<dim3(N_NODES / 16), dim3(256), 0, stream>>>(xt, dv, xpre);
        k_prop <<<dim3(N_NODES / 4), dim3(256), 0, stream>>>(xpre,
                 rowstart + (size_t)t * (N_NODES + 1),
                 csrp + (size_t)t * E_EDGES, dv, xagg);
        k_gemm1<<<dim3(N_NODES / 128, 2), dim3(256), 0, stream>>>(xagg, h, Wt1, bias3, z, hr);
        k_gemm2<<<dim3(N_NODES / 128), dim3(256), 0, stream>>>(xagg, hr, Wt2, bias3, z, h, outsum, t);
    }
    k_pool<<<dim3(B_GRAPHS), dim3(128), 0, stream>>>(outsum, Wlin, blin, out);
}